// Round 7
// baseline (465.413 us; speedup 1.0000x reference)
//
#include <hip/hip_runtime.h>

static inline int ceil_div(int a, int b){ return (a+b-1)/b; }

// ---------------- CSR build ----------------
__global__ __launch_bounds__(256) void k_hist(const int* __restrict__ dst, int E, int* __restrict__ cnt){
  int e = blockIdx.x*256 + threadIdx.x;
  if (e < E) atomicAdd(&cnt[dst[e]], 1);
}

__global__ __launch_bounds__(256) void k_scan_a(const int* __restrict__ cnt, int N, int* __restrict__ bsum){
  __shared__ int s[256];
  int t = threadIdx.x;
  int i0 = blockIdx.x*512 + 2*t;
  int a = (i0   < N) ? cnt[i0]   : 0;
  int b = (i0+1 < N) ? cnt[i0+1] : 0;
  s[t] = a + b;
  __syncthreads();
  for (int off=128; off>0; off>>=1){ if (t<off) s[t]+=s[t+off]; __syncthreads(); }
  if (t==0) bsum[blockIdx.x] = s[0];
}

// exclusive scan of bsum[0..nb), nb <= 1024
__global__ __launch_bounds__(256) void k_scan_b(int* __restrict__ bsum, int nb){
  __shared__ int s[256];
  int t = threadIdx.x;
  int v0=0,v1=0,v2=0,v3=0;
  int i0 = t*4;
  if (i0   < nb) v0 = bsum[i0];
  if (i0+1 < nb) v1 = bsum[i0+1];
  if (i0+2 < nb) v2 = bsum[i0+2];
  if (i0+3 < nb) v3 = bsum[i0+3];
  int tsum = v0+v1+v2+v3;
  s[t] = tsum;
  __syncthreads();
  for (int off=1; off<256; off<<=1){
    int v = (t>=off) ? s[t-off] : 0;
    __syncthreads();
    s[t] += v;
    __syncthreads();
  }
  int excl = s[t] - tsum;
  if (i0   < nb) bsum[i0]   = excl;
  if (i0+1 < nb) bsum[i0+1] = excl + v0;
  if (i0+2 < nb) bsum[i0+2] = excl + v0 + v1;
  if (i0+3 < nb) bsum[i0+3] = excl + v0 + v1 + v2;
}

__global__ __launch_bounds__(256) void k_scan_c(const int* __restrict__ cnt, int N,
                                                const int* __restrict__ bsum, int* __restrict__ offs){
  __shared__ int s[256];
  int t = threadIdx.x;
  int i0 = blockIdx.x*512 + 2*t;
  int a = (i0   < N) ? cnt[i0]   : 0;
  int b = (i0+1 < N) ? cnt[i0+1] : 0;
  int tsum = a+b;
  s[t] = tsum;
  __syncthreads();
  for (int off=1; off<256; off<<=1){
    int v = (t>=off) ? s[t-off] : 0;
    __syncthreads();
    s[t] += v;
    __syncthreads();
  }
  int excl = s[t] - tsum + bsum[blockIdx.x];
  if (i0   < N) offs[i0]   = excl;
  if (i0+1 < N) offs[i0+1] = excl + a;
}

// place: atomically bump offs; old value = absolute slot. After: offs[d] = beg+cnt.
__global__ __launch_bounds__(256) void k_place(const int* __restrict__ src, const int* __restrict__ dst, int E,
                                               int* __restrict__ offs, int* __restrict__ ss){
  int e = blockIdx.x*256 + threadIdx.x;
  if (e < E){
    int d = dst[e];
    int p = atomicAdd(&offs[d], 1);
    ss[p] = src[e];
  }
}

// ---------------- Fused: aggregate(layer1) -> h1=relu(agg@W1+b1) -> t1=h1@W2 ----------------
// One block = 64 nodes. Phase A: 4 waves gather 16 nodes each into sA (agg rows).
// Phase B: GEMM1 from sA, write h1 (global) + sA in place. Phase C: t1 from sA with W2^T in LDS.
__global__ __launch_bounds__(256) void k_fused1(const float* __restrict__ feats,
    const int* __restrict__ ss, const int* __restrict__ offs, const int* __restrict__ cnt,
    const float* __restrict__ W1, const float* __restrict__ b1,
    const float* __restrict__ W2,
    float* __restrict__ h1, float* __restrict__ t1, int N){
  __shared__ float sA[64*132];   // 33792 B
  __shared__ float sW[40*132];   // 21120 B : W1 chunk (4096 floats) / W2^T [40][132]
  int t = threadIdx.x;
  int r0 = blockIdx.x*64;

  // ---- Phase A: gather-aggregate 64 rows into sA ----
  {
    int wid = t >> 6, lane = t & 63;
    const float2* f2 = (const float2*)feats;
    for (int k2=0; k2<16; ++k2){
      int rr = wid*16 + k2;
      int w  = r0 + rr;
      float2 acc = make_float2(0.f, 0.f);
      if (w < N){
        int c   = __builtin_amdgcn_readfirstlane(cnt[w]);
        int beg = __builtin_amdgcn_readfirstlane(offs[w]) - c;  // offs is end after k_place
        acc = f2[(size_t)w*64 + lane];                          // self term
        int i = 0;
        for (; i+8 <= c; i += 8){                               // 8 row-loads in flight
          int s0=ss[beg+i  ], s1=ss[beg+i+1], s2=ss[beg+i+2], s3=ss[beg+i+3];
          int s4=ss[beg+i+4], s5=ss[beg+i+5], s6=ss[beg+i+6], s7=ss[beg+i+7];
          float2 a0=f2[(size_t)s0*64+lane], a1=f2[(size_t)s1*64+lane];
          float2 a2=f2[(size_t)s2*64+lane], a3=f2[(size_t)s3*64+lane];
          float2 a4=f2[(size_t)s4*64+lane], a5=f2[(size_t)s5*64+lane];
          float2 a6=f2[(size_t)s6*64+lane], a7=f2[(size_t)s7*64+lane];
          acc.x += ((a0.x+a1.x)+(a2.x+a3.x)) + ((a4.x+a5.x)+(a6.x+a7.x));
          acc.y += ((a0.y+a1.y)+(a2.y+a3.y)) + ((a4.y+a5.y)+(a6.y+a7.y));
        }
        for (; i < c; ++i){
          int s0 = ss[beg+i];
          float2 a = f2[(size_t)s0*64 + lane];
          acc.x += a.x; acc.y += a.y;
        }
        float inv = 1.0f / (float)(c + 1);
        acc.x *= inv; acc.y *= inv;
      }
      *(float2*)&sA[rr*132 + 2*lane] = acc;
    }
  }

  // ---- Phase B: h1 tile = relu(sA @ W1 + b1) ----
  int rg = t>>4, cg = t&15;      // rows {rg,rg+16,rg+32,rg+48}, cols {cg*4..+3, 64+cg*4..+3}
  float acc[4][8];
#pragma unroll
  for (int i=0;i<4;++i)
#pragma unroll
    for (int j=0;j<8;++j) acc[i][j]=0.f;

  for (int kc=0; kc<4; ++kc){
    __syncthreads();
#pragma unroll
    for (int it=0; it<4; ++it){
      int flat = it*1024 + t*4;
      *(float4*)&sW[flat] = *(const float4*)(W1 + kc*4096 + flat);
    }
    __syncthreads();               // (kc=0: also orders Phase-A sA writes before compute)
#pragma unroll 4
    for (int dd=0; dd<32; ++dd){
      int d = kc*32 + dd;
      float4 w0 = *(const float4*)&sW[dd*128 + cg*4];
      float4 w1 = *(const float4*)&sW[dd*128 + 64 + cg*4];
      float a0 = sA[(rg   )*132 + d];
      float a1 = sA[(rg+16)*132 + d];
      float a2 = sA[(rg+32)*132 + d];
      float a3 = sA[(rg+48)*132 + d];
      acc[0][0]+=a0*w0.x; acc[0][1]+=a0*w0.y; acc[0][2]+=a0*w0.z; acc[0][3]+=a0*w0.w;
      acc[0][4]+=a0*w1.x; acc[0][5]+=a0*w1.y; acc[0][6]+=a0*w1.z; acc[0][7]+=a0*w1.w;
      acc[1][0]+=a1*w0.x; acc[1][1]+=a1*w0.y; acc[1][2]+=a1*w0.z; acc[1][3]+=a1*w0.w;
      acc[1][4]+=a1*w1.x; acc[1][5]+=a1*w1.y; acc[1][6]+=a1*w1.z; acc[1][7]+=a1*w1.w;
      acc[2][0]+=a2*w0.x; acc[2][1]+=a2*w0.y; acc[2][2]+=a2*w0.z; acc[2][3]+=a2*w0.w;
      acc[2][4]+=a2*w1.x; acc[2][5]+=a2*w1.y; acc[2][6]+=a2*w1.z; acc[2][7]+=a2*w1.w;
      acc[3][0]+=a3*w0.x; acc[3][1]+=a3*w0.y; acc[3][2]+=a3*w0.z; acc[3][3]+=a3*w0.w;
      acc[3][4]+=a3*w1.x; acc[3][5]+=a3*w1.y; acc[3][6]+=a3*w1.z; acc[3][7]+=a3*w1.w;
    }
  }
  __syncthreads();   // all compute done: sA(agg) and sW(W1) dead

  // bias + relu; write h1 to global AND back into sA
  float4 bb0 = *(const float4*)(b1 + cg*4);
  float4 bb1 = *(const float4*)(b1 + 64 + cg*4);
#pragma unroll
  for (int i=0;i<4;++i){
    int rr = rg + i*16;
    int r  = r0 + rr;
    float4 o0, o1;
    o0.x = fmaxf(acc[i][0]+bb0.x, 0.f); o0.y = fmaxf(acc[i][1]+bb0.y, 0.f);
    o0.z = fmaxf(acc[i][2]+bb0.z, 0.f); o0.w = fmaxf(acc[i][3]+bb0.w, 0.f);
    o1.x = fmaxf(acc[i][4]+bb1.x, 0.f); o1.y = fmaxf(acc[i][5]+bb1.y, 0.f);
    o1.z = fmaxf(acc[i][6]+bb1.z, 0.f); o1.w = fmaxf(acc[i][7]+bb1.w, 0.f);
    *(float4*)&sA[rr*132 + cg*4]      = o0;
    *(float4*)&sA[rr*132 + 64 + cg*4] = o1;
    if (r < N){
      *(float4*)(h1 + (size_t)r*128 + cg*4)      = o0;
      *(float4*)(h1 + (size_t)r*128 + 64 + cg*4) = o1;
    }
  }
  // stage W2 transposed: sW[col*132 + d] = W2[d*40 + col]
#pragma unroll
  for (int it=0; it<5; ++it){
    int flat = it*1024 + t*4;
    float4 v = *(const float4*)(W2 + flat);
    const float* vp = (const float*)&v;
#pragma unroll
    for (int j=0;j<4;++j){
      int idx = flat + j;
      int d = idx / 40, col = idx % 40;
      sW[col*132 + d] = vp[j];
    }
  }
  __syncthreads();

  // ---- Phase C: t1 tile = h1_tile @ W2 (b128 reads over d for both operands) ----
  int rg2 = t>>3, cg2 = t&7;     // rows {rg2, rg2+32}, cols {cg2 + 8*jj}
  float a2c[2][5];
#pragma unroll
  for (int i=0;i<2;++i)
#pragma unroll
    for (int j=0;j<5;++j) a2c[i][j]=0.f;
  for (int d0=0; d0<32; ++d0){
    float4 a0 = *(const float4*)&sA[(rg2   )*132 + 4*d0];
    float4 a1 = *(const float4*)&sA[(rg2+32)*132 + 4*d0];
#pragma unroll
    for (int jj=0;jj<5;++jj){
      float4 wv = *(const float4*)&sW[(cg2+8*jj)*132 + 4*d0];
      a2c[0][jj] += a0.x*wv.x + a0.y*wv.y + a0.z*wv.z + a0.w*wv.w;
      a2c[1][jj] += a1.x*wv.x + a1.y*wv.y + a1.z*wv.z + a1.w*wv.w;
    }
  }
#pragma unroll
  for (int i=0;i<2;++i){
    int r = r0 + rg2 + i*32;
    if (r < N){
#pragma unroll
      for (int jj=0;jj<5;++jj) t1[(size_t)r*40 + cg2 + 8*jj] = a2c[i][jj];
    }
  }
}

// h2[v,:] = (sum_neigh t1[s,:] + t1[v,:]) / (deg+1) + b2
__global__ __launch_bounds__(256) void k_agg2(const float* __restrict__ t1,
    const int* __restrict__ ss, const int* __restrict__ offs, const int* __restrict__ cnt,
    const float* __restrict__ b2, float* __restrict__ h2, int N){
  int w = (int)((blockIdx.x*256u + threadIdx.x) >> 6);
  int lane = threadIdx.x & 63;
  if (w >= N) return;
  int c   = __builtin_amdgcn_readfirstlane(cnt[w]);
  int beg = __builtin_amdgcn_readfirstlane(offs[w]) - c;
  int l = (lane < 40) ? lane : 0;
  float acc = t1[(size_t)w*40 + l];
  int i = 0;
  for (; i+4 <= c; i += 4){
    int s0 = ss[beg+i], s1 = ss[beg+i+1], s2 = ss[beg+i+2], s3 = ss[beg+i+3];
    float a = t1[(size_t)s0*40 + l];
    float b = t1[(size_t)s1*40 + l];
    float cc= t1[(size_t)s2*40 + l];
    float d = t1[(size_t)s3*40 + l];
    acc += (a + b) + (cc + d);
  }
  for (; i < c; ++i) acc += t1[(size_t)ss[beg+i]*40 + l];
  float inv = 1.0f / (float)(c + 1);
  if (lane < 40) h2[(size_t)w*40 + lane] = acc*inv + b2[lane];
}

extern "C" void kernel_launch(void* const* d_in, const int* in_sizes, int n_in,
                              void* d_out, int out_size, void* d_ws, size_t ws_size,
                              hipStream_t stream){
  const float* feats = (const float*)d_in[0];
  const int*   src   = (const int*)d_in[1];
  const int*   dst   = (const int*)d_in[2];
  const float* W1    = (const float*)d_in[3];
  const float* b1    = (const float*)d_in[4];
  const float* W2    = (const float*)d_in[5];
  const float* b2    = (const float*)d_in[6];
  int N = in_sizes[0] / 128;
  int E = in_sizes[1];
  float* h1 = (float*)d_out;
  float* h2 = h1 + (size_t)N*128;

  size_t need = 0;
  auto lay = [&](size_t bytes)->size_t{ size_t p = need; need += (bytes + 511) & ~(size_t)511; return p; };
  size_t o_cnt    = lay((size_t)N*4);
  size_t o_offs   = lay((size_t)N*4);
  size_t o_bsum   = lay(4096);
  size_t o_ss     = lay((size_t)E*4);
  size_t o_t1     = lay((size_t)N*40*4);
  if (need > ws_size) return;

  char* wp = (char*)d_ws;
  int*   cnt    = (int*)(wp + o_cnt);
  int*   offs   = (int*)(wp + o_offs);
  int*   bsum   = (int*)(wp + o_bsum);
  int*   ss     = (int*)(wp + o_ss);
  float* t1     = (float*)(wp + o_t1);

  hipMemsetAsync(cnt, 0, (size_t)N*4, stream);

  int nb = ceil_div(N, 512);
  k_hist  <<<ceil_div(E,256), 256, 0, stream>>>(dst, E, cnt);
  k_scan_a<<<nb,              256, 0, stream>>>(cnt, N, bsum);
  k_scan_b<<<1,               256, 0, stream>>>(bsum, nb);
  k_scan_c<<<nb,              256, 0, stream>>>(cnt, N, bsum, offs);
  k_place <<<ceil_div(E,256), 256, 0, stream>>>(src, dst, E, offs, ss);

  k_fused1<<<ceil_div(N,64),  256, 0, stream>>>(feats, ss, offs, cnt, W1, b1, W2, h1, t1, N);
  k_agg2  <<<ceil_div(N,4),   256, 0, stream>>>(t1, ss, offs, cnt, b2, h2, N);
}

// Round 9
// 447.836 us; speedup vs baseline: 1.0392x; 1.0392x over previous
//
#include <hip/hip_runtime.h>

static inline int ceil_div(int a, int b){ return (a+b-1)/b; }

// ---------------- CSR build ----------------
__global__ __launch_bounds__(256) void k_hist(const int* __restrict__ dst, int E, int* __restrict__ cnt){
  int e = blockIdx.x*256 + threadIdx.x;
  if (e < E) atomicAdd(&cnt[dst[e]], 1);
}

__global__ __launch_bounds__(256) void k_scan_a(const int* __restrict__ cnt, int N, int* __restrict__ bsum){
  __shared__ int s[256];
  int t = threadIdx.x;
  int i0 = blockIdx.x*512 + 2*t;
  int a = (i0   < N) ? cnt[i0]   : 0;
  int b = (i0+1 < N) ? cnt[i0+1] : 0;
  s[t] = a + b;
  __syncthreads();
  for (int off=128; off>0; off>>=1){ if (t<off) s[t]+=s[t+off]; __syncthreads(); }
  if (t==0) bsum[blockIdx.x] = s[0];
}

// exclusive scan of bsum[0..nb), nb <= 1024
__global__ __launch_bounds__(256) void k_scan_b(int* __restrict__ bsum, int nb){
  __shared__ int s[256];
  int t = threadIdx.x;
  int v0=0,v1=0,v2=0,v3=0;
  int i0 = t*4;
  if (i0   < nb) v0 = bsum[i0];
  if (i0+1 < nb) v1 = bsum[i0+1];
  if (i0+2 < nb) v2 = bsum[i0+2];
  if (i0+3 < nb) v3 = bsum[i0+3];
  int tsum = v0+v1+v2+v3;
  s[t] = tsum;
  __syncthreads();
  for (int off=1; off<256; off<<=1){
    int v = (t>=off) ? s[t-off] : 0;
    __syncthreads();
    s[t] += v;
    __syncthreads();
  }
  int excl = s[t] - tsum;
  if (i0   < nb) bsum[i0]   = excl;
  if (i0+1 < nb) bsum[i0+1] = excl + v0;
  if (i0+2 < nb) bsum[i0+2] = excl + v0 + v1;
  if (i0+3 < nb) bsum[i0+3] = excl + v0 + v1 + v2;
}

__global__ __launch_bounds__(256) void k_scan_c(const int* __restrict__ cnt, int N,
                                                const int* __restrict__ bsum, int* __restrict__ offs){
  __shared__ int s[256];
  int t = threadIdx.x;
  int i0 = blockIdx.x*512 + 2*t;
  int a = (i0   < N) ? cnt[i0]   : 0;
  int b = (i0+1 < N) ? cnt[i0+1] : 0;
  int tsum = a+b;
  s[t] = tsum;
  __syncthreads();
  for (int off=1; off<256; off<<=1){
    int v = (t>=off) ? s[t-off] : 0;
    __syncthreads();
    s[t] += v;
    __syncthreads();
  }
  int excl = s[t] - tsum + bsum[blockIdx.x];
  if (i0   < N) offs[i0]   = excl;
  if (i0+1 < N) offs[i0+1] = excl + a;
}

// place: atomically bump offs; old value = absolute slot. After: offs[d] = beg+cnt.
__global__ __launch_bounds__(256) void k_place(const int* __restrict__ src, const int* __restrict__ dst, int E,
                                               int* __restrict__ offs, int* __restrict__ ss){
  int e = blockIdx.x*256 + threadIdx.x;
  if (e < E){
    int d = dst[e];
    int p = atomicAdd(&offs[d], 1);
    ss[p] = src[e];
  }
}

// ---------------- Layer 1 aggregate: r5-measured version (82.7us, 72% occ) ----------------
__global__ __launch_bounds__(256) void k_agg1(const float* __restrict__ feats,
    const int* __restrict__ ss, const int* __restrict__ offs, const int* __restrict__ cnt,
    float* __restrict__ aggout, int N){
  int w = (int)((blockIdx.x*256u + threadIdx.x) >> 6);
  int lane = threadIdx.x & 63;
  if (w >= N) return;
  int c   = __builtin_amdgcn_readfirstlane(cnt[w]);
  int beg = __builtin_amdgcn_readfirstlane(offs[w]) - c;   // offs is end after k_place
  const float2* f2 = (const float2*)feats;
  float2 acc = f2[(size_t)w*64 + lane];   // self term
  int i = 0;
  for (; i+4 <= c; i += 4){               // 4 row-loads in flight
    int s0 = ss[beg+i], s1 = ss[beg+i+1], s2 = ss[beg+i+2], s3 = ss[beg+i+3];
    float2 a = f2[(size_t)s0*64 + lane];
    float2 b = f2[(size_t)s1*64 + lane];
    float2 cc= f2[(size_t)s2*64 + lane];
    float2 d = f2[(size_t)s3*64 + lane];
    acc.x += (a.x + b.x) + (cc.x + d.x);
    acc.y += (a.y + b.y) + (cc.y + d.y);
  }
  for (; i < c; ++i){
    int s0 = ss[beg+i];
    float2 a = f2[(size_t)s0*64 + lane];
    acc.x += a.x; acc.y += a.y;
  }
  float inv = 1.0f / (float)(c + 1);
  float2 o; o.x = acc.x*inv; o.y = acc.y*inv;
  ((float2*)aggout)[(size_t)w*64 + lane] = o;
}

// ---------------- Fused GEMMs: h1 = relu(agg@W1+b1) (in-place) AND t1 = h1@W2 ----------------
// v2 inner loop: float4-over-K reads, base-pointer + immediate offsets, full unroll.
__global__ __launch_bounds__(256) void k_gemm12(float* __restrict__ h1,
    const float* __restrict__ W1, const float* __restrict__ b1,
    const float* __restrict__ W2, float* __restrict__ t1, int N){
  __shared__ float sA[64*132];   // 33792 B, stride 132 (528B, 16B-aligned rows)
  __shared__ float sW[5280];     // union: W1 chunk [32][128] (4096 f) / W2^T [40][132] (5280 f)
  int t = threadIdx.x;
  int r0 = blockIdx.x*64;
  // stage agg tile (h1 region currently holds agg)
  for (int it=0; it<8; ++it){
    int flat = it*1024 + t*4;
    int r = flat>>7, d = flat&127;
    float4 v = make_float4(0.f,0.f,0.f,0.f);
    if (r0+r < N) v = *(const float4*)(h1 + (size_t)(r0+r)*128 + d);
    *(float4*)&sA[r*132 + d] = v;
  }
  int rg = t>>4, cg = t&15;      // rows {rg,rg+16,rg+32,rg+48}, cols {cg*4..+3, 64+cg*4..+3}
  float acc[4][8];
#pragma unroll
  for (int i=0;i<4;++i)
#pragma unroll
    for (int j=0;j<8;++j) acc[i][j]=0.f;

  for (int kc=0; kc<4; ++kc){
    __syncthreads();
#pragma unroll
    for (int it=0; it<4; ++it){
      int flat = it*1024 + t*4;
      *(float4*)&sW[flat] = *(const float4*)(W1 + kc*4096 + flat);
    }
    __syncthreads();
    // base pointers: all inner offsets are compile-time immediates
    const float* a0p = &sA[(rg   )*132 + kc*32];
    const float* a1p = &sA[(rg+16)*132 + kc*32];
    const float* a2p = &sA[(rg+32)*132 + kc*32];
    const float* a3p = &sA[(rg+48)*132 + kc*32];
    const float* wp  = &sW[cg*4];
#pragma unroll
    for (int dq=0; dq<8; ++dq){          // 4 K-steps per iteration
      float4 a0 = *(const float4*)(a0p + dq*4);
      float4 a1 = *(const float4*)(a1p + dq*4);
      float4 a2 = *(const float4*)(a2p + dq*4);
      float4 a3 = *(const float4*)(a3p + dq*4);
      const float* a0f = (const float*)&a0;
      const float* a1f = (const float*)&a1;
      const float* a2f = (const float*)&a2;
      const float* a3f = (const float*)&a3;
#pragma unroll
      for (int j=0; j<4; ++j){
        float4 w0 = *(const float4*)(wp + (dq*4+j)*128);
        float4 w1 = *(const float4*)(wp + (dq*4+j)*128 + 64);
        float v0 = a0f[j], v1 = a1f[j], v2 = a2f[j], v3 = a3f[j];
        acc[0][0]+=v0*w0.x; acc[0][1]+=v0*w0.y; acc[0][2]+=v0*w0.z; acc[0][3]+=v0*w0.w;
        acc[0][4]+=v0*w1.x; acc[0][5]+=v0*w1.y; acc[0][6]+=v0*w1.z; acc[0][7]+=v0*w1.w;
        acc[1][0]+=v1*w0.x; acc[1][1]+=v1*w0.y; acc[1][2]+=v1*w0.z; acc[1][3]+=v1*w0.w;
        acc[1][4]+=v1*w1.x; acc[1][5]+=v1*w1.y; acc[1][6]+=v1*w1.z; acc[1][7]+=v1*w1.w;
        acc[2][0]+=v2*w0.x; acc[2][1]+=v2*w0.y; acc[2][2]+=v2*w0.z; acc[2][3]+=v2*w0.w;
        acc[2][4]+=v2*w1.x; acc[2][5]+=v2*w1.y; acc[2][6]+=v2*w1.z; acc[2][7]+=v2*w1.w;
        acc[3][0]+=v3*w0.x; acc[3][1]+=v3*w0.y; acc[3][2]+=v3*w0.z; acc[3][3]+=v3*w0.w;
        acc[3][4]+=v3*w1.x; acc[3][5]+=v3*w1.y; acc[3][6]+=v3*w1.z; acc[3][7]+=v3*w1.w;
      }
    }
  }
  __syncthreads();   // K-loop done everywhere: sA(agg) and sW(W1) dead

  // bias + relu; write h1 to global AND back into sA for phase C
  float4 bb0 = *(const float4*)(b1 + cg*4);
  float4 bb1 = *(const float4*)(b1 + 64 + cg*4);
#pragma unroll
  for (int i=0;i<4;++i){
    int rr = rg + i*16;
    int r  = r0 + rr;
    float4 o0, o1;
    o0.x = fmaxf(acc[i][0]+bb0.x, 0.f); o0.y = fmaxf(acc[i][1]+bb0.y, 0.f);
    o0.z = fmaxf(acc[i][2]+bb0.z, 0.f); o0.w = fmaxf(acc[i][3]+bb0.w, 0.f);
    o1.x = fmaxf(acc[i][4]+bb1.x, 0.f); o1.y = fmaxf(acc[i][5]+bb1.y, 0.f);
    o1.z = fmaxf(acc[i][6]+bb1.z, 0.f); o1.w = fmaxf(acc[i][7]+bb1.w, 0.f);
    *(float4*)&sA[rr*132 + cg*4]      = o0;
    *(float4*)&sA[rr*132 + 64 + cg*4] = o1;
    if (r < N){
      *(float4*)(h1 + (size_t)r*128 + cg*4)      = o0;
      *(float4*)(h1 + (size_t)r*128 + 64 + cg*4) = o1;
    }
  }
  // stage W2 transposed: sW[col*132 + d] = W2[d*40 + col]
#pragma unroll
  for (int it=0; it<5; ++it){
    int flat = it*1024 + t*4;
    float4 v = *(const float4*)(W2 + flat);
    const float* vp = (const float*)&v;
#pragma unroll
    for (int j=0;j<4;++j){
      int idx = flat + j;
      int d = idx / 40, col = idx % 40;
      sW[col*132 + d] = vp[j];
    }
  }
  __syncthreads();

  // ---- Phase C: t1 tile = h1_tile @ W2 (b128 over K for both operands, imm offsets) ----
  int rg2 = t>>3, cg2 = t&7;     // rows {rg2, rg2+32}, cols {cg2 + 8*jj}
  float a2c[2][5];
#pragma unroll
  for (int i=0;i<2;++i)
#pragma unroll
    for (int j=0;j<5;++j) a2c[i][j]=0.f;
  {
    const float* aB0 = &sA[(rg2   )*132];
    const float* aB1 = &sA[(rg2+32)*132];
    const float* wB0 = &sW[(cg2     )*132];
    const float* wB1 = &sW[(cg2+ 8)*132];
    const float* wB2 = &sW[(cg2+16)*132];
    const float* wB3 = &sW[(cg2+24)*132];
    const float* wB4 = &sW[(cg2+32)*132];
#pragma unroll 8
    for (int d0=0; d0<32; ++d0){
      float4 a0 = *(const float4*)(aB0 + 4*d0);
      float4 a1 = *(const float4*)(aB1 + 4*d0);
      float4 w0 = *(const float4*)(wB0 + 4*d0);
      float4 w1 = *(const float4*)(wB1 + 4*d0);
      float4 w2 = *(const float4*)(wB2 + 4*d0);
      float4 w3 = *(const float4*)(wB3 + 4*d0);
      float4 w4 = *(const float4*)(wB4 + 4*d0);
      a2c[0][0] += a0.x*w0.x + a0.y*w0.y + a0.z*w0.z + a0.w*w0.w;
      a2c[0][1] += a0.x*w1.x + a0.y*w1.y + a0.z*w1.z + a0.w*w1.w;
      a2c[0][2] += a0.x*w2.x + a0.y*w2.y + a0.z*w2.z + a0.w*w2.w;
      a2c[0][3] += a0.x*w3.x + a0.y*w3.y + a0.z*w3.z + a0.w*w3.w;
      a2c[0][4] += a0.x*w4.x + a0.y*w4.y + a0.z*w4.z + a0.w*w4.w;
      a2c[1][0] += a1.x*w0.x + a1.y*w0.y + a1.z*w0.z + a1.w*w0.w;
      a2c[1][1] += a1.x*w1.x + a1.y*w1.y + a1.z*w1.z + a1.w*w1.w;
      a2c[1][2] += a1.x*w2.x + a1.y*w2.y + a1.z*w2.z + a1.w*w2.w;
      a2c[1][3] += a1.x*w3.x + a1.y*w3.y + a1.z*w3.z + a1.w*w3.w;
      a2c[1][4] += a1.x*w4.x + a1.y*w4.y + a1.z*w4.z + a1.w*w4.w;
    }
  }
#pragma unroll
  for (int i=0;i<2;++i){
    int r = r0 + rg2 + i*32;
    if (r < N){
#pragma unroll
      for (int jj=0;jj<5;++jj) t1[(size_t)r*40 + cg2 + 8*jj] = a2c[i][jj];
    }
  }
}

// h2[v,:] = (sum_neigh t1[s,:] + t1[v,:]) / (deg+1) + b2
__global__ __launch_bounds__(256) void k_agg2(const float* __restrict__ t1,
    const int* __restrict__ ss, const int* __restrict__ offs, const int* __restrict__ cnt,
    const float* __restrict__ b2, float* __restrict__ h2, int N){
  int w = (int)((blockIdx.x*256u + threadIdx.x) >> 6);
  int lane = threadIdx.x & 63;
  if (w >= N) return;
  int c   = __builtin_amdgcn_readfirstlane(cnt[w]);
  int beg = __builtin_amdgcn_readfirstlane(offs[w]) - c;
  int l = (lane < 40) ? lane : 0;
  float acc = t1[(size_t)w*40 + l];
  int i = 0;
  for (; i+4 <= c; i += 4){
    int s0 = ss[beg+i], s1 = ss[beg+i+1], s2 = ss[beg+i+2], s3 = ss[beg+i+3];
    float a = t1[(size_t)s0*40 + l];
    float b = t1[(size_t)s1*40 + l];
    float cc= t1[(size_t)s2*40 + l];
    float d = t1[(size_t)s3*40 + l];
    acc += (a + b) + (cc + d);
  }
  for (; i < c; ++i) acc += t1[(size_t)ss[beg+i]*40 + l];
  float inv = 1.0f / (float)(c + 1);
  if (lane < 40) h2[(size_t)w*40 + lane] = acc*inv + b2[lane];
}

extern "C" void kernel_launch(void* const* d_in, const int* in_sizes, int n_in,
                              void* d_out, int out_size, void* d_ws, size_t ws_size,
                              hipStream_t stream){
  const float* feats = (const float*)d_in[0];
  const int*   src   = (const int*)d_in[1];
  const int*   dst   = (const int*)d_in[2];
  const float* W1    = (const float*)d_in[3];
  const float* b1    = (const float*)d_in[4];
  const float* W2    = (const float*)d_in[5];
  const float* b2    = (const float*)d_in[6];
  int N = in_sizes[0] / 128;
  int E = in_sizes[1];
  float* h1 = (float*)d_out;
  float* h2 = h1 + (size_t)N*128;

  size_t need = 0;
  auto lay = [&](size_t bytes)->size_t{ size_t p = need; need += (bytes + 511) & ~(size_t)511; return p; };
  size_t o_cnt    = lay((size_t)N*4);
  size_t o_offs   = lay((size_t)N*4);
  size_t o_bsum   = lay(4096);
  size_t o_ss     = lay((size_t)E*4);
  size_t o_t1     = lay((size_t)N*40*4);
  if (need > ws_size) return;

  char* wp = (char*)d_ws;
  int*   cnt    = (int*)(wp + o_cnt);
  int*   offs   = (int*)(wp + o_offs);
  int*   bsum   = (int*)(wp + o_bsum);
  int*   ss     = (int*)(wp + o_ss);
  float* t1     = (float*)(wp + o_t1);

  hipMemsetAsync(cnt, 0, (size_t)N*4, stream);

  int nb = ceil_div(N, 512);
  k_hist  <<<ceil_div(E,256), 256, 0, stream>>>(dst, E, cnt);
  k_scan_a<<<nb,              256, 0, stream>>>(cnt, N, bsum);
  k_scan_b<<<1,               256, 0, stream>>>(bsum, nb);
  k_scan_c<<<nb,              256, 0, stream>>>(cnt, N, bsum, offs);
  k_place <<<ceil_div(E,256), 256, 0, stream>>>(src, dst, E, offs, ss);

  k_agg1  <<<ceil_div(N,4),   256, 0, stream>>>(feats, ss, offs, cnt, h1, N);
  k_gemm12<<<ceil_div(N,64),  256, 0, stream>>>(h1, W1, b1, W2, t1, N);
  k_agg2  <<<ceil_div(N,4),   256, 0, stream>>>(t1, ss, offs, cnt, b2, h2, N);
}

// Round 10
// 415.859 us; speedup vs baseline: 1.1192x; 1.0769x over previous
//
#include <hip/hip_runtime.h>

static inline int ceil_div(int a, int b){ return (a+b-1)/b; }

// ---------------- CSR build ----------------
__global__ __launch_bounds__(256) void k_hist(const int* __restrict__ dst, int E, int* __restrict__ cnt){
  int e = blockIdx.x*256 + threadIdx.x;
  if (e < E) atomicAdd(&cnt[dst[e]], 1);
}

__global__ __launch_bounds__(256) void k_scan_a(const int* __restrict__ cnt, int N, int* __restrict__ bsum){
  __shared__ int s[256];
  int t = threadIdx.x;
  int i0 = blockIdx.x*512 + 2*t;
  int a = (i0   < N) ? cnt[i0]   : 0;
  int b = (i0+1 < N) ? cnt[i0+1] : 0;
  s[t] = a + b;
  __syncthreads();
  for (int off=128; off>0; off>>=1){ if (t<off) s[t]+=s[t+off]; __syncthreads(); }
  if (t==0) bsum[blockIdx.x] = s[0];
}

// exclusive scan of bsum[0..nb), nb <= 1024
__global__ __launch_bounds__(256) void k_scan_b(int* __restrict__ bsum, int nb){
  __shared__ int s[256];
  int t = threadIdx.x;
  int v0=0,v1=0,v2=0,v3=0;
  int i0 = t*4;
  if (i0   < nb) v0 = bsum[i0];
  if (i0+1 < nb) v1 = bsum[i0+1];
  if (i0+2 < nb) v2 = bsum[i0+2];
  if (i0+3 < nb) v3 = bsum[i0+3];
  int tsum = v0+v1+v2+v3;
  s[t] = tsum;
  __syncthreads();
  for (int off=1; off<256; off<<=1){
    int v = (t>=off) ? s[t-off] : 0;
    __syncthreads();
    s[t] += v;
    __syncthreads();
  }
  int excl = s[t] - tsum;
  if (i0   < nb) bsum[i0]   = excl;
  if (i0+1 < nb) bsum[i0+1] = excl + v0;
  if (i0+2 < nb) bsum[i0+2] = excl + v0 + v1;
  if (i0+3 < nb) bsum[i0+3] = excl + v0 + v1 + v2;
}

__global__ __launch_bounds__(256) void k_scan_c(const int* __restrict__ cnt, int N,
                                                const int* __restrict__ bsum, int* __restrict__ offs){
  __shared__ int s[256];
  int t = threadIdx.x;
  int i0 = blockIdx.x*512 + 2*t;
  int a = (i0   < N) ? cnt[i0]   : 0;
  int b = (i0+1 < N) ? cnt[i0+1] : 0;
  int tsum = a+b;
  s[t] = tsum;
  __syncthreads();
  for (int off=1; off<256; off<<=1){
    int v = (t>=off) ? s[t-off] : 0;
    __syncthreads();
    s[t] += v;
    __syncthreads();
  }
  int excl = s[t] - tsum + bsum[blockIdx.x];
  if (i0   < N) offs[i0]   = excl;
  if (i0+1 < N) offs[i0+1] = excl + a;
}

// place: atomically bump offs; old value = absolute slot. After: offs[d] = beg+cnt.
__global__ __launch_bounds__(256) void k_place(const int* __restrict__ src, const int* __restrict__ dst, int E,
                                               int* __restrict__ offs, int* __restrict__ ss){
  int e = blockIdx.x*256 + threadIdx.x;
  if (e < E){
    int d = dst[e];
    int p = atomicAdd(&offs[d], 1);
    ss[p] = src[e];
  }
}

// ---------------- Layer 1 aggregate: r5-measured version (82.7us, 72% occ) ----------------
__global__ __launch_bounds__(256) void k_agg1(const float* __restrict__ feats,
    const int* __restrict__ ss, const int* __restrict__ offs, const int* __restrict__ cnt,
    float* __restrict__ aggout, int N){
  int w = (int)((blockIdx.x*256u + threadIdx.x) >> 6);
  int lane = threadIdx.x & 63;
  if (w >= N) return;
  int c   = __builtin_amdgcn_readfirstlane(cnt[w]);
  int beg = __builtin_amdgcn_readfirstlane(offs[w]) - c;   // offs is end after k_place
  const float2* f2 = (const float2*)feats;
  float2 acc = f2[(size_t)w*64 + lane];   // self term
  int i = 0;
  for (; i+4 <= c; i += 4){               // 4 row-loads in flight
    int s0 = ss[beg+i], s1 = ss[beg+i+1], s2 = ss[beg+i+2], s3 = ss[beg+i+3];
    float2 a = f2[(size_t)s0*64 + lane];
    float2 b = f2[(size_t)s1*64 + lane];
    float2 cc= f2[(size_t)s2*64 + lane];
    float2 d = f2[(size_t)s3*64 + lane];
    acc.x += (a.x + b.x) + (cc.x + d.x);
    acc.y += (a.y + b.y) + (cc.y + d.y);
  }
  for (; i < c; ++i){
    int s0 = ss[beg+i];
    float2 a = f2[(size_t)s0*64 + lane];
    acc.x += a.x; acc.y += a.y;
  }
  float inv = 1.0f / (float)(c + 1);
  float2 o; o.x = acc.x*inv; o.y = acc.y*inv;
  ((float2*)aggout)[(size_t)w*64 + lane] = o;
}

// ---------------- Fused GEMMs v3: 32-row tile for 4 blocks/CU occupancy ----------------
// h1 = relu(agg@W1+b1) (in-place) AND t1 = h1@W2.
// LDS: sA 32x132 (16896B) + sW 5280f (21120B) = 38016B -> 4 blocks/CU (cap 50% occ).
__global__ __launch_bounds__(256, 4) void k_gemm12(float* __restrict__ h1,
    const float* __restrict__ W1, const float* __restrict__ b1,
    const float* __restrict__ W2, float* __restrict__ t1, int N){
  __shared__ float sA[32*132];   // 16896 B
  __shared__ float sW[5280];     // union: W1 chunk [32][128] (4096f) / W2^T [40][132] (5280f)
  int t = threadIdx.x;
  int r0 = blockIdx.x*32;
  // stage agg tile (h1 region currently holds agg): 4096 floats, 4 float4/thread
#pragma unroll
  for (int it=0; it<4; ++it){
    int flat = it*1024 + t*4;
    int r = flat>>7, d = flat&127;
    float4 v = make_float4(0.f,0.f,0.f,0.f);
    if (r0+r < N) v = *(const float4*)(h1 + (size_t)(r0+r)*128 + d);
    *(float4*)&sA[r*132 + d] = v;
  }
  int rg = t>>4, cg = t&15;      // rows {rg, rg+16}, cols {cg*4..+3, 64+cg*4..+3}
  float acc[2][8];
#pragma unroll
  for (int i=0;i<2;++i)
#pragma unroll
    for (int j=0;j<8;++j) acc[i][j]=0.f;

  for (int kc=0; kc<4; ++kc){
    __syncthreads();
#pragma unroll
    for (int it=0; it<4; ++it){
      int flat = it*1024 + t*4;
      *(float4*)&sW[flat] = *(const float4*)(W1 + kc*4096 + flat);
    }
    __syncthreads();               // (kc=0: also orders Phase-A staging)
#pragma unroll 4
    for (int dd=0; dd<32; ++dd){
      int d = kc*32 + dd;
      float4 w0 = *(const float4*)&sW[dd*128 + cg*4];
      float4 w1 = *(const float4*)&sW[dd*128 + 64 + cg*4];
      float a0 = sA[(rg   )*132 + d];
      float a1 = sA[(rg+16)*132 + d];
      acc[0][0]+=a0*w0.x; acc[0][1]+=a0*w0.y; acc[0][2]+=a0*w0.z; acc[0][3]+=a0*w0.w;
      acc[0][4]+=a0*w1.x; acc[0][5]+=a0*w1.y; acc[0][6]+=a0*w1.z; acc[0][7]+=a0*w1.w;
      acc[1][0]+=a1*w0.x; acc[1][1]+=a1*w0.y; acc[1][2]+=a1*w0.z; acc[1][3]+=a1*w0.w;
      acc[1][4]+=a1*w1.x; acc[1][5]+=a1*w1.y; acc[1][6]+=a1*w1.z; acc[1][7]+=a1*w1.w;
    }
  }
  __syncthreads();   // K-loop done everywhere: sA(agg) and sW(W1) dead

  // bias + relu; write h1 to global AND back into sA for phase C
  float4 bb0 = *(const float4*)(b1 + cg*4);
  float4 bb1 = *(const float4*)(b1 + 64 + cg*4);
#pragma unroll
  for (int i=0;i<2;++i){
    int rr = rg + i*16;
    int r  = r0 + rr;
    float4 o0, o1;
    o0.x = fmaxf(acc[i][0]+bb0.x, 0.f); o0.y = fmaxf(acc[i][1]+bb0.y, 0.f);
    o0.z = fmaxf(acc[i][2]+bb0.z, 0.f); o0.w = fmaxf(acc[i][3]+bb0.w, 0.f);
    o1.x = fmaxf(acc[i][4]+bb1.x, 0.f); o1.y = fmaxf(acc[i][5]+bb1.y, 0.f);
    o1.z = fmaxf(acc[i][6]+bb1.z, 0.f); o1.w = fmaxf(acc[i][7]+bb1.w, 0.f);
    *(float4*)&sA[rr*132 + cg*4]      = o0;
    *(float4*)&sA[rr*132 + 64 + cg*4] = o1;
    if (r < N){
      *(float4*)(h1 + (size_t)r*128 + cg*4)      = o0;
      *(float4*)(h1 + (size_t)r*128 + 64 + cg*4) = o1;
    }
  }
  // stage W2 transposed: sW[col*132 + d] = W2[d*40 + col]
  // (scatter-write conflicts measured ~1% of kernel cycles — acceptable for b128 phase-C reads)
#pragma unroll
  for (int it=0; it<5; ++it){
    int flat = it*1024 + t*4;
    float4 v = *(const float4*)(W2 + flat);
    const float* vp = (const float*)&v;
#pragma unroll
    for (int j=0;j<4;++j){
      int idx = flat + j;
      int d = idx / 40, col = idx % 40;
      sW[col*132 + d] = vp[j];
    }
  }
  __syncthreads();

  // ---- Phase C: t1 tile = h1_tile @ W2 (b128 over K for both operands) ----
  int rg2 = t>>3, cg2 = t&7;     // row rg2 (0..31), cols {cg2 + 8*jj, jj=0..4}
  float a2c[5];
#pragma unroll
  for (int j=0;j<5;++j) a2c[j]=0.f;
  {
    const float* aB0 = &sA[rg2*132];
    const float* wB0 = &sW[(cg2     )*132];
    const float* wB1 = &sW[(cg2+ 8)*132];
    const float* wB2 = &sW[(cg2+16)*132];
    const float* wB3 = &sW[(cg2+24)*132];
    const float* wB4 = &sW[(cg2+32)*132];
#pragma unroll 4
    for (int d0=0; d0<32; ++d0){
      float4 a0 = *(const float4*)(aB0 + 4*d0);
      float4 w0 = *(const float4*)(wB0 + 4*d0);
      float4 w1 = *(const float4*)(wB1 + 4*d0);
      float4 w2 = *(const float4*)(wB2 + 4*d0);
      float4 w3 = *(const float4*)(wB3 + 4*d0);
      float4 w4 = *(const float4*)(wB4 + 4*d0);
      a2c[0] += a0.x*w0.x + a0.y*w0.y + a0.z*w0.z + a0.w*w0.w;
      a2c[1] += a0.x*w1.x + a0.y*w1.y + a0.z*w1.z + a0.w*w1.w;
      a2c[2] += a0.x*w2.x + a0.y*w2.y + a0.z*w2.z + a0.w*w2.w;
      a2c[3] += a0.x*w3.x + a0.y*w3.y + a0.z*w3.z + a0.w*w3.w;
      a2c[4] += a0.x*w4.x + a0.y*w4.y + a0.z*w4.z + a0.w*w4.w;
    }
  }
  {
    int r = r0 + rg2;
    if (r < N){
#pragma unroll
      for (int jj=0;jj<5;++jj) t1[(size_t)r*40 + cg2 + 8*jj] = a2c[jj];
    }
  }
}

// h2[v,:] = (sum_neigh t1[s,:] + t1[v,:]) / (deg+1) + b2
__global__ __launch_bounds__(256) void k_agg2(const float* __restrict__ t1,
    const int* __restrict__ ss, const int* __restrict__ offs, const int* __restrict__ cnt,
    const float* __restrict__ b2, float* __restrict__ h2, int N){
  int w = (int)((blockIdx.x*256u + threadIdx.x) >> 6);
  int lane = threadIdx.x & 63;
  if (w >= N) return;
  int c   = __builtin_amdgcn_readfirstlane(cnt[w]);
  int beg = __builtin_amdgcn_readfirstlane(offs[w]) - c;
  int l = (lane < 40) ? lane : 0;
  float acc = t1[(size_t)w*40 + l];
  int i = 0;
  for (; i+4 <= c; i += 4){
    int s0 = ss[beg+i], s1 = ss[beg+i+1], s2 = ss[beg+i+2], s3 = ss[beg+i+3];
    float a = t1[(size_t)s0*40 + l];
    float b = t1[(size_t)s1*40 + l];
    float cc= t1[(size_t)s2*40 + l];
    float d = t1[(size_t)s3*40 + l];
    acc += (a + b) + (cc + d);
  }
  for (; i < c; ++i) acc += t1[(size_t)ss[beg+i]*40 + l];
  float inv = 1.0f / (float)(c + 1);
  if (lane < 40) h2[(size_t)w*40 + lane] = acc*inv + b2[lane];
}

extern "C" void kernel_launch(void* const* d_in, const int* in_sizes, int n_in,
                              void* d_out, int out_size, void* d_ws, size_t ws_size,
                              hipStream_t stream){
  const float* feats = (const float*)d_in[0];
  const int*   src   = (const int*)d_in[1];
  const int*   dst   = (const int*)d_in[2];
  const float* W1    = (const float*)d_in[3];
  const float* b1    = (const float*)d_in[4];
  const float* W2    = (const float*)d_in[5];
  const float* b2    = (const float*)d_in[6];
  int N = in_sizes[0] / 128;
  int E = in_sizes[1];
  float* h1 = (float*)d_out;
  float* h2 = h1 + (size_t)N*128;

  size_t need = 0;
  auto lay = [&](size_t bytes)->size_t{ size_t p = need; need += (bytes + 511) & ~(size_t)511; return p; };
  size_t o_cnt    = lay((size_t)N*4);
  size_t o_offs   = lay((size_t)N*4);
  size_t o_bsum   = lay(4096);
  size_t o_ss     = lay((size_t)E*4);
  size_t o_t1     = lay((size_t)N*40*4);
  if (need > ws_size) return;

  char* wp = (char*)d_ws;
  int*   cnt    = (int*)(wp + o_cnt);
  int*   offs   = (int*)(wp + o_offs);
  int*   bsum   = (int*)(wp + o_bsum);
  int*   ss     = (int*)(wp + o_ss);
  float* t1     = (float*)(wp + o_t1);

  hipMemsetAsync(cnt, 0, (size_t)N*4, stream);

  int nb = ceil_div(N, 512);
  k_hist  <<<ceil_div(E,256), 256, 0, stream>>>(dst, E, cnt);
  k_scan_a<<<nb,              256, 0, stream>>>(cnt, N, bsum);
  k_scan_b<<<1,               256, 0, stream>>>(bsum, nb);
  k_scan_c<<<nb,              256, 0, stream>>>(cnt, N, bsum, offs);
  k_place <<<ceil_div(E,256), 256, 0, stream>>>(src, dst, E, offs, ss);

  k_agg1  <<<ceil_div(N,4),   256, 0, stream>>>(feats, ss, offs, cnt, h1, N);
  k_gemm12<<<ceil_div(N,32),  256, 0, stream>>>(h1, W1, b1, W2, t1, N);
  k_agg2  <<<ceil_div(N,4),   256, 0, stream>>>(t1, ss, offs, cnt, b2, h2, N);
}